// Round 2
// baseline (309.760 us; speedup 1.0000x reference)
//
#include <hip/hip_runtime.h>
#include <stdint.h>

#define BATCH 32
#define NV 1024
#define EMB 64

typedef __attribute__((ext_vector_type(8))) short bf16x8;
typedef __attribute__((ext_vector_type(4))) float f32x4;

__device__ __forceinline__ unsigned short f2b(float f) {
  unsigned int u = __builtin_bit_cast(unsigned int, f);
  u += 0x7fffu + ((u >> 16) & 1u);   // RNE
  return (unsigned short)(u >> 16);
}
__device__ __forceinline__ float b2f(unsigned short s) {
  unsigned int u = ((unsigned int)s) << 16;
  return __builtin_bit_cast(float, u);
}

__device__ __forceinline__ void gll16(void* lds, const void* gsrc) {
  __builtin_amdgcn_global_load_lds(
      (const __attribute__((address_space(1))) unsigned int*)gsrc,
      (__attribute__((address_space(3))) unsigned int*)lds, 16, 0, 0);
}

// ---------------------------------------------------------------------------
// k_prep: deg row-sums, graph f32->bf16, w34 = W3@W4, emb1 = relu(base)
// written transposed embT[b][e][n]. grid 32*16, 256 threads.
// ---------------------------------------------------------------------------
__global__ __launch_bounds__(256) void k_prep(
    const float* __restrict__ graph, const float* __restrict__ Xv,
    const float* __restrict__ W1, const float* __restrict__ W3,
    const float* __restrict__ W4,
    unsigned short* __restrict__ G16, float* __restrict__ degp,
    float* __restrict__ w34g, unsigned short* __restrict__ embT)
{
  __shared__ float w34s[EMB];
  __shared__ __align__(16) unsigned short ebT[EMB][68];  // pad 68: 2-way max
  const int tid = threadIdx.x;
  const int b = blockIdx.x >> 4;
  const int rb = blockIdx.x & 15;          // 64 rows per block
  if (tid < EMB) {
    float s = 0.f;
    const float* w3r = W3 + tid * EMB;
#pragma unroll
    for (int k = 0; k < EMB; ++k) s += w3r[k] * W4[k];
    w34s[tid] = s;
    if (blockIdx.x == 0) w34g[tid] = s;
  }
  __syncthreads();
  const int wv = tid >> 6, lane = tid & 63;
  const float w1v = W1[lane];
  const float w34v = w34s[lane];
  for (int i = 0; i < 16; ++i) {
    const int row = rb * 64 + wv * 16 + i;
    const float4* gr = (const float4*)(graph + ((size_t)b * NV + row) * NV);
    float part = 0.f;
    ushort4 outp[4];
#pragma unroll
    for (int c = 0; c < 4; ++c) {
      float4 v = gr[c * 64 + lane];
      part += (v.x + v.y) + (v.z + v.w);
      outp[c].x = f2b(v.x); outp[c].y = f2b(v.y);
      outp[c].z = f2b(v.z); outp[c].w = f2b(v.w);
    }
    ushort4* g16r = (ushort4*)(G16 + ((size_t)b * NV + row) * NV);
#pragma unroll
    for (int c = 0; c < 4; ++c) g16r[c * 64 + lane] = outp[c];
#pragma unroll
    for (int d = 1; d < 64; d <<= 1) part += __shfl_xor(part, d);
    const float deg = part;
    if (lane == 0) degp[b * NV + row] = deg;
    const float xv = Xv[b * NV + row];
    const float bs = xv * w1v + deg * w34v;
    ebT[lane][wv * 16 + i] = f2b(fmaxf(bs, 0.f));
  }
  __syncthreads();
  // write emb1 transposed, coalesced 32B segments
  const int e = tid >> 2, q = tid & 3;
  ushort4* dst = (ushort4*)(embT + ((size_t)(b * EMB + e)) * NV + rb * 64 + q * 16);
  const ushort4* srcr = (const ushort4*)(&ebT[e][q * 16]);
#pragma unroll
  for (int c = 0; c < 4; ++c) dst[c] = srcr[c];
}

// ---------------------------------------------------------------------------
// k_step: embout = relu(base + (G @ embin) @ W2^T), embT layout in/out.
// grid 32*16 (64-row tiles), 256 threads = 4 waves (2m x 2n of 32x32).
// ---------------------------------------------------------------------------
__global__ __launch_bounds__(256) void k_step(
    const unsigned short* __restrict__ G16,
    const unsigned short* __restrict__ embin,
    unsigned short* __restrict__ embout,
    const float* __restrict__ W2, const float* __restrict__ W1,
    const float* __restrict__ w34g, const float* __restrict__ Xv,
    const float* __restrict__ degp)
{
  __shared__ __align__(16) char lds[16384];
  char* At = lds;          // 64x64 bf16 tile of G (swizzled), reused for S
  char* Bt = lds + 8192;   // 64x64 bf16 tile of embT
  const int tid = threadIdx.x;
  const int lane = tid & 63;
  const int wv = tid >> 6;
  const int wm = wv >> 1;   // row-half of block tile
  const int wn = wv & 1;    // col-half
  const int b = blockIdx.x >> 4;
  const int mblk = blockIdx.x & 15;
  const int l15 = lane & 15, l4 = lane >> 4;

  // preload W2 B-fragments (bf16) and per-lane base factors
  bf16x8 w2f[2][2];
  float w1e[2], w34e[2];
#pragma unroll
  for (int e16 = 0; e16 < 2; ++e16) {
    const int eg = wn * 32 + e16 * 16 + l15;
    w1e[e16] = W1[eg];
    w34e[e16] = w34g[eg];
#pragma unroll
    for (int kk = 0; kk < 2; ++kk) {
      const float* src = W2 + eg * 64 + kk * 32 + l4 * 8;
      bf16x8 f;
#pragma unroll
      for (int j = 0; j < 8; ++j) f[j] = (short)f2b(src[j]);
      w2f[e16][kk] = f;
    }
  }

  f32x4 acc[2][2] = {};
  const size_t gbase = ((size_t)b * NV + mblk * 64) * NV;
  const size_t ebase = (size_t)b * EMB * NV;

  for (int kt = 0; kt < 16; ++kt) {
    // stage A tile (pre-swizzled global source -> linear LDS = swizzled content)
#pragma unroll
    for (int i = 0; i < 2; ++i) {
      const int cc = i * 256 + tid;
      const int lrow = cc >> 3, lcg = cc & 7;
      const int gcg = lcg ^ (lrow & 7);
      gll16(At + (i * 256 + wv * 64) * 16,
            G16 + gbase + (size_t)lrow * NV + kt * 64 + gcg * 8);
    }
    // stage B tile (embT rows = output feature, contiguous along k)
#pragma unroll
    for (int i = 0; i < 2; ++i) {
      const int cc = i * 256 + tid;
      const int er = cc >> 3, lcg = cc & 7;
      const int gcg = lcg ^ (er & 7);
      gll16(Bt + (i * 256 + wv * 64) * 16,
            embin + ebase + (size_t)er * NV + kt * 64 + gcg * 8);
    }
    __syncthreads();
#pragma unroll
    for (int kk = 0; kk < 2; ++kk) {
      bf16x8 af[2], bf[2];
      const int gq = kk * 4 + l4;
#pragma unroll
      for (int m16 = 0; m16 < 2; ++m16) {
        const int row = wm * 32 + m16 * 16 + l15;
        af[m16] = *(const bf16x8*)(At + row * 128 + ((gq ^ (row & 7)) << 4));
      }
#pragma unroll
      for (int n16 = 0; n16 < 2; ++n16) {
        const int er = wn * 32 + n16 * 16 + l15;
        bf[n16] = *(const bf16x8*)(Bt + er * 128 + ((gq ^ (er & 7)) << 4));
      }
#pragma unroll
      for (int m16 = 0; m16 < 2; ++m16)
#pragma unroll
        for (int n16 = 0; n16 < 2; ++n16)
          acc[m16][n16] = __builtin_amdgcn_mfma_f32_16x16x32_bf16(
              af[m16], bf[n16], acc[m16][n16], 0, 0, 0);
    }
    __syncthreads();
  }

  // ---- epilogue: S -> LDS (swizzled bf16), then out2 = S @ W2^T ----
#pragma unroll
  for (int m16 = 0; m16 < 2; ++m16)
#pragma unroll
    for (int n16 = 0; n16 < 2; ++n16)
#pragma unroll
      for (int r = 0; r < 4; ++r) {
        const int m = wm * 32 + m16 * 16 + l4 * 4 + r;
        const int n = wn * 32 + n16 * 16 + l15;
        const int addr = m * 128 + (((n >> 3) ^ (m & 7)) << 4) + (n & 7) * 2;
        *(unsigned short*)(At + addr) = f2b(acc[m16][n16][r]);
      }
  __syncthreads();

  f32x4 acc2[2][2] = {};
#pragma unroll
  for (int kk = 0; kk < 2; ++kk) {
    bf16x8 sa[2];
    const int gq = kk * 4 + l4;
#pragma unroll
    for (int m16 = 0; m16 < 2; ++m16) {
      const int row = wm * 32 + m16 * 16 + l15;
      sa[m16] = *(const bf16x8*)(At + row * 128 + ((gq ^ (row & 7)) << 4));
    }
#pragma unroll
    for (int m16 = 0; m16 < 2; ++m16)
#pragma unroll
      for (int e16 = 0; e16 < 2; ++e16)
        acc2[m16][e16] = __builtin_amdgcn_mfma_f32_16x16x32_bf16(
            sa[m16], w2f[e16][kk], acc2[m16][e16], 0, 0, 0);
  }

  // + base (recomputed from Xv, deg), relu, write transposed embT
#pragma unroll
  for (int m16 = 0; m16 < 2; ++m16) {
    const int m0 = mblk * 64 + wm * 32 + m16 * 16 + l4 * 4;
    float xv[4], dg[4];
#pragma unroll
    for (int r = 0; r < 4; ++r) {
      xv[r] = Xv[b * NV + m0 + r];
      dg[r] = degp[b * NV + m0 + r];
    }
#pragma unroll
    for (int e16 = 0; e16 < 2; ++e16) {
      const int eg = wn * 32 + e16 * 16 + l15;
      ushort4 pk;
      unsigned short* pks = (unsigned short*)&pk;
#pragma unroll
      for (int r = 0; r < 4; ++r) {
        const float bs = xv[r] * w1e[e16] + dg[r] * w34e[e16];
        pks[r] = f2b(fmaxf(acc2[m16][e16][r] + bs, 0.f));
      }
      *(ushort4*)(embout + ((size_t)(b * EMB + eg)) * NV + m0) = pk;
    }
  }
}

// ---------------------------------------------------------------------------
// k_red: s6[b] = sum_e W5[e]*relu(W6 @ (sum_n emb[b,n,:])). grid 32, 256 thr.
// ---------------------------------------------------------------------------
__global__ __launch_bounds__(256) void k_red(
    const unsigned short* __restrict__ embT, const float* __restrict__ W6,
    const float* __restrict__ W5, float* __restrict__ s6)
{
  __shared__ float part[256];
  __shared__ float esum[EMB];
  const int b = blockIdx.x, tid = threadIdx.x;
  const int e = tid >> 2, q = tid & 3;
  const unsigned short* rowp = embT + ((size_t)(b * EMB + e)) * NV;
  float s = 0.f;
  for (int j = 0; j < 32; ++j) {
    const ushort4* p = (const ushort4*)(rowp + q * 8 + j * 32);
    ushort4 a = p[0], c = p[1];
    s += (b2f(a.x) + b2f(a.y)) + (b2f(a.z) + b2f(a.w)) +
         (b2f(c.x) + b2f(c.y)) + (b2f(c.z) + b2f(c.w));
  }
  part[tid] = s;
  __syncthreads();
  if (tid < EMB)
    esum[tid] = part[tid * 4] + part[tid * 4 + 1] + part[tid * 4 + 2] + part[tid * 4 + 3];
  __syncthreads();
  if (tid < EMB) {
    float v6 = 0.f;
    const float* w6r = W6 + tid * EMB;
#pragma unroll
    for (int k = 0; k < EMB; ++k) v6 += w6r[k] * esum[k];
    float contrib = W5[tid] * fmaxf(v6, 0.f);
#pragma unroll
    for (int d = 1; d < 64; d <<= 1) contrib += __shfl_xor(contrib, d);
    if (tid == 0) s6[b] = contrib;
  }
}

// ---------------------------------------------------------------------------
// k_out: out[b,n] = s6[b] + sum_e W5[64+e]*relu(sum_k emb[b,n,k]*W7[e,k])
// grid 32*4 (256 vertices each), 256 threads.
// ---------------------------------------------------------------------------
__global__ __launch_bounds__(256) void k_out(
    const unsigned short* __restrict__ embT, const float* __restrict__ W7,
    const float* __restrict__ W5, const float* __restrict__ s6,
    float* __restrict__ out)
{
  __shared__ __align__(16) unsigned short et[EMB][256];
  const int tid = threadIdx.x;
  const int b = blockIdx.x >> 2;
  const int n0 = (blockIdx.x & 3) * 256;
#pragma unroll
  for (int i = 0; i < 8; ++i) {
    const int c = i * 256 + tid;           // 2048 16B chunks
    const int k = c >> 5, off = (c & 31) * 8;
    *(uint4*)&et[k][off] =
        *(const uint4*)(embT + ((size_t)(b * EMB + k)) * NV + n0 + off);
  }
  __syncthreads();
  float ev[64];
#pragma unroll
  for (int k = 0; k < 64; ++k) ev[k] = b2f(et[k][tid]);
  float s7 = 0.f;
  for (int e = 0; e < 64; ++e) {
    const float* w7r = W7 + e * 64;        // uniform -> scalar loads
    float a = 0.f;
#pragma unroll
    for (int k = 0; k < 64; ++k) a += ev[k] * w7r[k];
    s7 += W5[64 + e] * fmaxf(a, 0.f);
  }
  out[b * NV + n0 + tid] = s6[b] + s7;
}

// ---------------------------------------------------------------------------
extern "C" void kernel_launch(void* const* d_in, const int* in_sizes, int n_in,
                              void* d_out, int out_size, void* d_ws, size_t ws_size,
                              hipStream_t stream) {
  const float* graph = (const float*)d_in[0];
  const float* Xv = (const float*)d_in[1];
  const float* W1 = (const float*)d_in[2];
  const float* W2 = (const float*)d_in[3];
  const float* W3 = (const float*)d_in[4];
  const float* W4 = (const float*)d_in[5];
  const float* W5 = (const float*)d_in[6];
  const float* W6 = (const float*)d_in[7];
  const float* W7 = (const float*)d_in[8];
  float* out = (float*)d_out;
  char* ws = (char*)d_ws;

  unsigned short* G16 = (unsigned short*)ws;                       // 64 MB
  unsigned short* embA = (unsigned short*)(ws + 67108864);         // 4 MB
  unsigned short* embB = (unsigned short*)(ws + 71303168);         // 4 MB
  float* degp = (float*)(ws + 75497472);                           // 128 KB
  float* w34g = (float*)(ws + 75628544);                           // 256 B
  float* s6 = (float*)(ws + 75628800);                             // 128 B

  k_prep<<<512, 256, 0, stream>>>(graph, Xv, W1, W3, W4, G16, degp, w34g, embA);
  k_step<<<512, 256, 0, stream>>>(G16, embA, embB, W2, W1, w34g, Xv, degp);
  k_step<<<512, 256, 0, stream>>>(G16, embB, embA, W2, W1, w34g, Xv, degp);
  k_step<<<512, 256, 0, stream>>>(G16, embA, embB, W2, W1, w34g, Xv, degp);
  k_red<<<32, 256, 0, stream>>>(embB, W6, W5, s6);
  k_out<<<128, 256, 0, stream>>>(embB, W7, W5, s6, out);
}